// Round 7
// baseline (193.154 us; speedup 1.0000x reference)
//
#include <hip/hip_runtime.h>
#include <math.h>

#define N_NODES 100000
#define N_EDGES 1000000
#define HDIM 128
#define N_NONLOOP (N_EDGES - N_NODES)          // 900000 edges needing atomics

typedef float  vfloat4 __attribute__((ext_vector_type(4)));

__device__ __forceinline__ float get_invtau(const int* __restrict__ training_step) {
    int step = training_step[0];
    float tau;
    if (step == -1) {
        tau = 0.1f;  // TEMP_EVAL
    } else {
        float frac = fminf((float)step / 10000.0f, 1.0f);
        tau = 1.0f + (0.1f - 1.0f) * frac;
    }
    return 1.0f / tau;
}

__device__ __forceinline__ float wave_reduce(float v) {
    #pragma unroll
    for (int off = 32; off > 0; off >>= 1) v += __shfl_down(v, off, 64);
    return v;
}

// ---------------------------------------------------------------------------
// Fused precompute + table stage 1.
// All blocks: pack edge-state indices (1 thread/edge), node_pack, zero acc.
// Blocks 0..255 additionally compute uv[1024] (one wave per combine_W row).
// ---------------------------------------------------------------------------
__global__ __launch_bounds__(256) void precompute_tab1(
    const int* __restrict__ node_states,
    const int* __restrict__ edge_states,
    const float* __restrict__ s,
    const float* __restrict__ cW,
    const float* __restrict__ kW, const float* __restrict__ pW,
    const float* __restrict__ pnW, const float* __restrict__ iW,
    const int* __restrict__ tstep,
    unsigned char* __restrict__ es_idx,
    float2* __restrict__ node_pack,
    float* __restrict__ acc,
    float* __restrict__ loss_out,
    float* __restrict__ uv)
{
    const int e = blockIdx.x * blockDim.x + threadIdx.x;
    if (e < N_EDGES) {
        int4 st = ((const int4*)edge_states)[e];
        es_idx[e] = (unsigned char)(st.x + 2 * st.y + 4 * st.z + 8 * st.w);
    }
    if (e < N_NODES) {
        int4 st = ((const int4*)node_states)[e];
        const int idx = st.x + 2 * st.y + 4 * st.z + 8 * st.w;
        float2 np;
        np.x = s[e];
        np.y = __int_as_float(idx);
        node_pack[e] = np;
        acc[e] = 0.f;
    }
    if (e == 0) *loss_out = 0.f;

    // -------- table stage 1 on the first 256 blocks --------
    if (blockIdx.x < 256) {
        __shared__ float wd[512];  // wdiff[h][d]
        const float invtau = get_invtau(tstep);
        for (int i = threadIdx.x; i < 512; i += 256) {
            const int h = i >> 7, d = i & 127;
            const float* W = (h == 0) ? kW : (h == 1) ? pW : (h == 2) ? pnW : iW;
            wd[i] = W[2 * d] - W[2 * d + 1];
        }
        __syncthreads();

        const int row  = blockIdx.x * 4 + (threadIdx.x >> 6);  // 0..1023
        const int lane = threadIdx.x & 63;
        const int half = row >> 9;
        const int r    = row & 511;
        const int h    = r >> 7, d = r & 127;
        const int cwrow = half * 128 + d;

        float p = cW[cwrow * 128 + lane]      * wd[h * 128 + lane]
                + cW[cwrow * 128 + 64 + lane] * wd[h * 128 + 64 + lane];
        p = wave_reduce(p);
        if (lane == 0) uv[row] = p * invtau;
    }
}

// ---------------------------------------------------------------------------
// Table stage 2: tabs as float4-per-index:
//   [0..15] A4 by ei, [16..31] B4 by ni, [32] C4.
// ---------------------------------------------------------------------------
__global__ void tab_stage2(const float* __restrict__ node_emb,
                           const float* __restrict__ edge_emb,
                           const float* __restrict__ cb,
                           const float* __restrict__ kW, const float* __restrict__ kb,
                           const float* __restrict__ pW, const float* __restrict__ pb,
                           const float* __restrict__ pnW, const float* __restrict__ pnb,
                           const float* __restrict__ iW, const float* __restrict__ ib,
                           const int* __restrict__ tstep,
                           const float* __restrict__ uv,
                           float* __restrict__ tabs)
{
    const int w = blockIdx.x * 4 + (threadIdx.x >> 6);  // 0..131
    if (w >= 132) return;
    const int lane = threadIdx.x & 63;
    const float invtau = get_invtau(tstep);

    float p;
    if (w < 128) {
        const int isB = w >> 6, h = (w >> 4) & 3, i = w & 15;
        const float* emb = isB ? node_emb : edge_emb;
        const float* uvp = uv + isB * 512 + h * 128;
        p = emb[i * 128 + lane] * uvp[lane] + emb[i * 128 + 64 + lane] * uvp[64 + lane];
    } else {
        const int h = w - 128;
        const float* W = (h == 0) ? kW : (h == 1) ? pW : (h == 2) ? pnW : iW;
        p = cb[lane]      * (W[2 * lane] - W[2 * lane + 1])
          + cb[64 + lane] * (W[2 * (64 + lane)] - W[2 * (64 + lane) + 1]);
    }
    p = wave_reduce(p);
    if (lane == 0) {
        if (w < 64) {
            const int h = (w >> 4) & 3, i = w & 15;
            tabs[i * 4 + h] = p;
        } else if (w < 128) {
            const int h = (w >> 4) & 3, i = w & 15;
            tabs[64 + i * 4 + h] = p;
        } else {
            const int h = w - 128;
            const float* b = (h == 0) ? kb : (h == 1) ? pb : (h == 2) ? pnb : ib;
            tabs[128 + h] = (p + b[0] - b[1]) * invtau;
        }
    }
}

// ---------------------------------------------------------------------------
// Non-loop edges only (e in [N_NODES, N_EDGES)). 1 edge/thread for max wave
// supply (3516 blocks). 3 gathers/edge: es_idx[rev] (1B), node_pack[src] (8B),
// node_pack[dst].x (4B).
// ---------------------------------------------------------------------------
__global__ __launch_bounds__(256) void edge_kernel(
    const float* __restrict__ s,
    const int* __restrict__ src,
    const int* __restrict__ dst,
    const int* __restrict__ brev,
    const unsigned char* __restrict__ es_idx,
    const float2* __restrict__ node_pack,
    const float* __restrict__ tabs,
    const float* __restrict__ target,
    float* __restrict__ acc,
    float* __restrict__ out,
    float* __restrict__ loss_out)
{
    __shared__ float4 sf[33];  // [0..15] A, [16..31] B, [32] C
    if (threadIdx.x < 33) sf[threadIdx.x] = ((const float4*)tabs)[threadIdx.x];
    __syncthreads();

    const int t = blockIdx.x * blockDim.x + threadIdx.x;   // 0 .. 899999
    float lsum = 0.f;

    if (t < N_NONLOOP) {
        const int e = N_NODES + t;
        const int rev = brev[e];
        const int si  = src[e];
        const int di  = dst[e];
        const float sv = s[e];
        const float tg = target[e];

        // 3 scattered reads, issued back-to-back
        const int    ei = es_idx[rev];
        const float2 np = node_pack[si];
        const float  sd = node_pack[di].x;

        const int   ni = __float_as_int(np.y);
        const float ss = np.x;

        const float4 a  = sf[ei];
        const float4 b  = sf[16 + ni];
        const float4 c4 = sf[32];
        const float lk  = a.x + b.x + c4.x;
        const float lp  = a.y + b.y + c4.y;
        const float lpn = a.z + b.z + c4.z;
        const float li  = a.w + b.w + c4.w;
        const float pk  = 1.f / (1.f + __expf(-lk));
        const float pp  = 1.f / (1.f + __expf(-lp));
        const float ppn = 1.f / (1.f + __expf(-lpn));
        const float pi  = 1.f / (1.f + __expf(-li));

        const float s_wo = sv - sd;
        const float s_w  = s_wo + ss;
        unsafeAtomicAdd(&acc[di], pp * s_wo + ppn * s_w);

        const float ov = pi + sv * pk;
        __builtin_nontemporal_store(ov, &out[e]);
        const float d = tg - ov;
        lsum += d * d;
    }

    lsum = wave_reduce(lsum);
    __shared__ float wsum[4];
    const int lane = threadIdx.x & 63, wid = threadIdx.x >> 6;
    if (lane == 0) wsum[wid] = lsum;
    __syncthreads();
    if (threadIdx.x == 0) {
        const float tot = wsum[0] + wsum[1] + wsum[2] + wsum[3];
        atomicAdd(loss_out, tot * (1.0f / (float)N_EDGES));
    }
}

// ---------------------------------------------------------------------------
// Loop edges (e < N_NODES): src=dst=e so s_wo=0; push contribution ppn*s[e]
// is local (no atomic). out[e] = pi + s[e]*(pk + ppn) + acc[e].
// ---------------------------------------------------------------------------
__global__ __launch_bounds__(256) void finalize_nodes(
    const int* __restrict__ brev,
    const unsigned char* __restrict__ es_idx,
    const float2* __restrict__ node_pack,
    const float* __restrict__ tabs,
    const float* __restrict__ target,
    const float* __restrict__ acc,
    float* __restrict__ out,
    float* __restrict__ loss_out)
{
    __shared__ float4 sf[33];
    if (threadIdx.x < 33) sf[threadIdx.x] = ((const float4*)tabs)[threadIdx.x];
    __syncthreads();

    const int n = blockIdx.x * blockDim.x + threadIdx.x;
    float sq = 0.f;
    if (n < N_NODES) {
        const int    rev = brev[n];
        const int    ei  = es_idx[rev];
        const float2 np  = node_pack[n];
        const int    ni  = __float_as_int(np.y);
        const float  sv  = np.x;

        const float4 a = sf[ei];
        const float4 b = sf[16 + ni];
        const float4 c4 = sf[32];
        const float lk  = a.x + b.x + c4.x;
        const float lpn = a.z + b.z + c4.z;
        const float li  = a.w + b.w + c4.w;
        const float pk  = 1.f / (1.f + __expf(-lk));
        const float ppn = 1.f / (1.f + __expf(-lpn));
        const float pi  = 1.f / (1.f + __expf(-li));

        const float v = pi + sv * (pk + ppn) + acc[n];
        out[n] = v;
        const float d = target[n] - v;
        sq = d * d;
    }
    sq = wave_reduce(sq);
    __shared__ float wsum[4];
    const int lane = threadIdx.x & 63, wid = threadIdx.x >> 6;
    if (lane == 0) wsum[wid] = sq;
    __syncthreads();
    if (threadIdx.x == 0) {
        const float tot = wsum[0] + wsum[1] + wsum[2] + wsum[3];
        atomicAdd(loss_out, tot * (1.0f / (float)N_EDGES));
    }
}

extern "C" void kernel_launch(void* const* d_in, const int* in_sizes, int n_in,
                              void* d_out, int out_size, void* d_ws, size_t ws_size,
                              hipStream_t stream) {
    const int*   node_states   = (const int*)d_in[0];
    const int*   edge_states   = (const int*)d_in[1];
    const float* scalars       = (const float*)d_in[2];
    const int*   edge_index    = (const int*)d_in[3];
    const int*   brev          = (const int*)d_in[4];
    const float* batch_scalars = (const float*)d_in[5];
    // d_in[6] = processor_step (batch axis-1 size 1 -> index 0)
    const int*   training_step = (const int*)d_in[7];
    const float* node_emb  = (const float*)d_in[8];
    const float* edge_emb  = (const float*)d_in[9];
    const float* combine_W = (const float*)d_in[10];
    const float* combine_b = (const float*)d_in[11];
    const float* keep_W  = (const float*)d_in[12];
    const float* keep_b  = (const float*)d_in[13];
    const float* push_W  = (const float*)d_in[14];
    const float* push_b  = (const float*)d_in[15];
    const float* pushn_W = (const float*)d_in[16];
    const float* pushn_b = (const float*)d_in[17];
    const float* inc_W   = (const float*)d_in[18];
    const float* inc_b   = (const float*)d_in[19];

    float* out = (float*)d_out;  // [0..E) new_scalars, [E] loss

    char* ws = (char*)d_ws;
    float*  tabs = (float*)ws;                                   // 132 floats (pad 1 KiB)
    float*  uv   = (float*)(ws + 1024);                          // 1024 floats (4 KiB)
    float*  acc  = (float*)(ws + 1024 + 4096);                   // N floats (400 KB)
    float2* node_pack = (float2*)(ws + 1024 + 4096 + (size_t)N_NODES * 4);  // N float2 (800 KB)
    unsigned char* es_idx = (unsigned char*)(ws + 1024 + 4096 + (size_t)N_NODES * 12); // E bytes

    const int* srcp = edge_index;
    const int* dstp = edge_index + N_EDGES;

    precompute_tab1<<<(N_EDGES + 255) / 256, 256, 0, stream>>>(
        node_states, edge_states, scalars,
        combine_W, keep_W, push_W, pushn_W, inc_W, training_step,
        es_idx, node_pack, acc, out + N_EDGES, uv);

    tab_stage2<<<33, 256, 0, stream>>>(node_emb, edge_emb, combine_b,
                                       keep_W, keep_b, push_W, push_b,
                                       pushn_W, pushn_b, inc_W, inc_b,
                                       training_step, uv, tabs);

    edge_kernel<<<(N_NONLOOP + 255) / 256, 256, 0, stream>>>(
        scalars, srcp, dstp, brev, es_idx, node_pack, tabs, batch_scalars,
        acc, out, out + N_EDGES);

    finalize_nodes<<<(N_NODES + 255) / 256, 256, 0, stream>>>(
        brev, es_idx, node_pack, tabs, batch_scalars, acc, out, out + N_EDGES);
}

// Round 8
// 177.501 us; speedup vs baseline: 1.0882x; 1.0882x over previous
//
#include <hip/hip_runtime.h>
#include <math.h>

#define N_NODES 100000
#define N_EDGES 1000000
#define HDIM 128
#define N_NONLOOP (N_EDGES - N_NODES)          // 900000 edges needing atomics

typedef float  vfloat4 __attribute__((ext_vector_type(4)));

__device__ __forceinline__ float get_invtau(const int* __restrict__ training_step) {
    int step = training_step[0];
    float tau;
    if (step == -1) {
        tau = 0.1f;  // TEMP_EVAL
    } else {
        float frac = fminf((float)step / 10000.0f, 1.0f);
        tau = 1.0f + (0.1f - 1.0f) * frac;
    }
    return 1.0f / tau;
}

__device__ __forceinline__ float wave_reduce(float v) {
    #pragma unroll
    for (int off = 32; off > 0; off >>= 1) v += __shfl_down(v, off, 64);
    return v;
}

// ---------------------------------------------------------------------------
// Fused node precompute + table stage 1 (391 blocks).
// All blocks: node_pack[n] = {s[n], ns_idx[n]}, acc[n]=0.
// Blocks 0..255: uv[1024] (one wave per combine_W row).
// ---------------------------------------------------------------------------
__global__ __launch_bounds__(256) void precompute_tab1(
    const int* __restrict__ node_states,
    const float* __restrict__ s,
    const float* __restrict__ cW,
    const float* __restrict__ kW, const float* __restrict__ pW,
    const float* __restrict__ pnW, const float* __restrict__ iW,
    const int* __restrict__ tstep,
    float2* __restrict__ node_pack,
    float* __restrict__ acc,
    float* __restrict__ loss_out,
    float* __restrict__ uv)
{
    const int n = blockIdx.x * blockDim.x + threadIdx.x;
    if (n < N_NODES) {
        int4 st = ((const int4*)node_states)[n];
        const int idx = st.x + 2 * st.y + 4 * st.z + 8 * st.w;
        float2 np;
        np.x = s[n];
        np.y = __int_as_float(idx);
        node_pack[n] = np;
        acc[n] = 0.f;
    }
    if (n == 0) *loss_out = 0.f;

    // -------- table stage 1 on the first 256 blocks --------
    if (blockIdx.x < 256) {
        __shared__ float wd[512];  // wdiff[h][d]
        const float invtau = get_invtau(tstep);
        for (int i = threadIdx.x; i < 512; i += 256) {
            const int h = i >> 7, d = i & 127;
            const float* W = (h == 0) ? kW : (h == 1) ? pW : (h == 2) ? pnW : iW;
            wd[i] = W[2 * d] - W[2 * d + 1];
        }
        __syncthreads();

        const int row  = blockIdx.x * 4 + (threadIdx.x >> 6);  // 0..1023
        const int lane = threadIdx.x & 63;
        const int half = row >> 9;
        const int r    = row & 511;
        const int h    = r >> 7, d = r & 127;
        const int cwrow = half * 128 + d;

        float p = cW[cwrow * 128 + lane]      * wd[h * 128 + lane]
                + cW[cwrow * 128 + 64 + lane] * wd[h * 128 + 64 + lane];
        p = wave_reduce(p);
        if (lane == 0) uv[row] = p * invtau;
    }
}

// ---------------------------------------------------------------------------
// Table stage 2: tabs as float4-per-index:
//   [0..15] A4 by ei, [16..31] B4 by ni, [32] C4.
// ---------------------------------------------------------------------------
__global__ void tab_stage2(const float* __restrict__ node_emb,
                           const float* __restrict__ edge_emb,
                           const float* __restrict__ cb,
                           const float* __restrict__ kW, const float* __restrict__ kb,
                           const float* __restrict__ pW, const float* __restrict__ pb,
                           const float* __restrict__ pnW, const float* __restrict__ pnb,
                           const float* __restrict__ iW, const float* __restrict__ ib,
                           const int* __restrict__ tstep,
                           const float* __restrict__ uv,
                           float* __restrict__ tabs)
{
    const int w = blockIdx.x * 4 + (threadIdx.x >> 6);  // 0..131
    if (w >= 132) return;
    const int lane = threadIdx.x & 63;
    const float invtau = get_invtau(tstep);

    float p;
    if (w < 128) {
        const int isB = w >> 6, h = (w >> 4) & 3, i = w & 15;
        const float* emb = isB ? node_emb : edge_emb;
        const float* uvp = uv + isB * 512 + h * 128;
        p = emb[i * 128 + lane] * uvp[lane] + emb[i * 128 + 64 + lane] * uvp[64 + lane];
    } else {
        const int h = w - 128;
        const float* W = (h == 0) ? kW : (h == 1) ? pW : (h == 2) ? pnW : iW;
        p = cb[lane]      * (W[2 * lane] - W[2 * lane + 1])
          + cb[64 + lane] * (W[2 * (64 + lane)] - W[2 * (64 + lane) + 1]);
    }
    p = wave_reduce(p);
    if (lane == 0) {
        if (w < 64) {
            const int h = (w >> 4) & 3, i = w & 15;
            tabs[i * 4 + h] = p;
        } else if (w < 128) {
            const int h = (w >> 4) & 3, i = w & 15;
            tabs[64 + i * 4 + h] = p;
        } else {
            const int h = w - 128;
            const float* b = (h == 0) ? kb : (h == 1) ? pb : (h == 2) ? pnb : ib;
            tabs[128 + h] = (p + b[0] - b[1]) * invtau;
        }
    }
}

// ---------------------------------------------------------------------------
// Non-loop edges (e in [N_NODES, N_EDGES)). 4 edges/thread (best measured
// config). 3 gathers/edge: edge_states int4 (16B), node_pack[src] (8B),
// node_pack[dst].x (4B). Atomic floor ~55-60us for 0.9M device atomics.
// ---------------------------------------------------------------------------
__global__ __launch_bounds__(256) void edge_kernel(
    const float* __restrict__ s,
    const int* __restrict__ src,
    const int* __restrict__ dst,
    const int* __restrict__ brev,
    const int* __restrict__ edge_states,
    const float2* __restrict__ node_pack,
    const float* __restrict__ tabs,
    const float* __restrict__ target,
    float* __restrict__ acc,
    float* __restrict__ out,
    float* __restrict__ loss_out)
{
    __shared__ float4 sf[33];  // [0..15] A, [16..31] B, [32] C
    if (threadIdx.x < 33) sf[threadIdx.x] = ((const float4*)tabs)[threadIdx.x];
    __syncthreads();

    const int t = blockIdx.x * blockDim.x + threadIdx.x;   // 0 .. 224999
    float lsum = 0.f;

    if (t < N_NONLOOP / 4) {
        const int g = (N_NODES / 4) + t;  // 16B-aligned quad index
        const int4   rv = ((const int4*)brev)[g];
        const int4   sr = ((const int4*)src)[g];
        const int4   ds = ((const int4*)dst)[g];
        const float4 sv = ((const float4*)s)[g];
        const vfloat4 tg = __builtin_nontemporal_load(&((const vfloat4*)target)[g]);

        const int rvv[4] = {rv.x, rv.y, rv.z, rv.w};
        const int srv[4] = {sr.x, sr.y, sr.z, sr.w};
        const int dsv[4] = {ds.x, ds.y, ds.z, ds.w};
        const float svv[4] = {sv.x, sv.y, sv.z, sv.w};
        const float tgv[4] = {tg.x, tg.y, tg.z, tg.w};

        // 12 independent gathers issued up front
        int4  es[4];
        float2 np[4];
        float sd[4];
        #pragma unroll
        for (int j = 0; j < 4; ++j) {
            es[j] = ((const int4*)edge_states)[rvv[j]];
            np[j] = node_pack[srv[j]];
            sd[j] = node_pack[dsv[j]].x;
        }

        const float4 c4 = sf[32];
        float ov[4];
        #pragma unroll
        for (int j = 0; j < 4; ++j) {
            const int ei = es[j].x + 2 * es[j].y + 4 * es[j].z + 8 * es[j].w;
            const int   ni = __float_as_int(np[j].y);
            const float ss = np[j].x;
            const float4 a = sf[ei];
            const float4 b = sf[16 + ni];
            const float lk  = a.x + b.x + c4.x;
            const float lp  = a.y + b.y + c4.y;
            const float lpn = a.z + b.z + c4.z;
            const float li  = a.w + b.w + c4.w;
            const float pk  = 1.f / (1.f + __expf(-lk));
            const float pp  = 1.f / (1.f + __expf(-lp));
            const float ppn = 1.f / (1.f + __expf(-lpn));
            const float pi  = 1.f / (1.f + __expf(-li));

            const float s_wo = svv[j] - sd[j];
            const float s_w  = s_wo + ss;
            unsafeAtomicAdd(&acc[dsv[j]], pp * s_wo + ppn * s_w);

            ov[j] = pi + svv[j] * pk;
            const float d = tgv[j] - ov[j];
            lsum += d * d;
        }
        vfloat4 o4 = {ov[0], ov[1], ov[2], ov[3]};
        __builtin_nontemporal_store(o4, &((vfloat4*)out)[g]);
    }

    lsum = wave_reduce(lsum);
    __shared__ float wsum[4];
    const int lane = threadIdx.x & 63, wid = threadIdx.x >> 6;
    if (lane == 0) wsum[wid] = lsum;
    __syncthreads();
    if (threadIdx.x == 0) {
        const float tot = wsum[0] + wsum[1] + wsum[2] + wsum[3];
        atomicAdd(loss_out, tot * (1.0f / (float)N_EDGES));
    }
}

// ---------------------------------------------------------------------------
// Loop edges (e < N_NODES): src=dst=e so s_wo=0; push contribution ppn*s[e]
// is local (no atomic). out[e] = pi + s[e]*(pk + ppn) + acc[e].
// ---------------------------------------------------------------------------
__global__ __launch_bounds__(256) void finalize_nodes(
    const int* __restrict__ brev,
    const int* __restrict__ edge_states,
    const float2* __restrict__ node_pack,
    const float* __restrict__ tabs,
    const float* __restrict__ target,
    const float* __restrict__ acc,
    float* __restrict__ out,
    float* __restrict__ loss_out)
{
    __shared__ float4 sf[33];
    if (threadIdx.x < 33) sf[threadIdx.x] = ((const float4*)tabs)[threadIdx.x];
    __syncthreads();

    const int n = blockIdx.x * blockDim.x + threadIdx.x;
    float sq = 0.f;
    if (n < N_NODES) {
        const int    rev = brev[n];
        const int4   est = ((const int4*)edge_states)[rev];
        const int    ei  = est.x + 2 * est.y + 4 * est.z + 8 * est.w;
        const float2 np  = node_pack[n];
        const int    ni  = __float_as_int(np.y);
        const float  sv  = np.x;

        const float4 a = sf[ei];
        const float4 b = sf[16 + ni];
        const float4 c4 = sf[32];
        const float lk  = a.x + b.x + c4.x;
        const float lpn = a.z + b.z + c4.z;
        const float li  = a.w + b.w + c4.w;
        const float pk  = 1.f / (1.f + __expf(-lk));
        const float ppn = 1.f / (1.f + __expf(-lpn));
        const float pi  = 1.f / (1.f + __expf(-li));

        const float v = pi + sv * (pk + ppn) + acc[n];
        out[n] = v;
        const float d = target[n] - v;
        sq = d * d;
    }
    sq = wave_reduce(sq);
    __shared__ float wsum[4];
    const int lane = threadIdx.x & 63, wid = threadIdx.x >> 6;
    if (lane == 0) wsum[wid] = sq;
    __syncthreads();
    if (threadIdx.x == 0) {
        const float tot = wsum[0] + wsum[1] + wsum[2] + wsum[3];
        atomicAdd(loss_out, tot * (1.0f / (float)N_EDGES));
    }
}

extern "C" void kernel_launch(void* const* d_in, const int* in_sizes, int n_in,
                              void* d_out, int out_size, void* d_ws, size_t ws_size,
                              hipStream_t stream) {
    const int*   node_states   = (const int*)d_in[0];
    const int*   edge_states   = (const int*)d_in[1];
    const float* scalars       = (const float*)d_in[2];
    const int*   edge_index    = (const int*)d_in[3];
    const int*   brev          = (const int*)d_in[4];
    const float* batch_scalars = (const float*)d_in[5];
    // d_in[6] = processor_step (batch axis-1 size 1 -> index 0)
    const int*   training_step = (const int*)d_in[7];
    const float* node_emb  = (const float*)d_in[8];
    const float* edge_emb  = (const float*)d_in[9];
    const float* combine_W = (const float*)d_in[10];
    const float* combine_b = (const float*)d_in[11];
    const float* keep_W  = (const float*)d_in[12];
    const float* keep_b  = (const float*)d_in[13];
    const float* push_W  = (const float*)d_in[14];
    const float* push_b  = (const float*)d_in[15];
    const float* pushn_W = (const float*)d_in[16];
    const float* pushn_b = (const float*)d_in[17];
    const float* inc_W   = (const float*)d_in[18];
    const float* inc_b   = (const float*)d_in[19];

    float* out = (float*)d_out;  // [0..E) new_scalars, [E] loss

    char* ws = (char*)d_ws;
    float*  tabs = (float*)ws;                                   // 132 floats (pad 1 KiB)
    float*  uv   = (float*)(ws + 1024);                          // 1024 floats (4 KiB)
    float*  acc  = (float*)(ws + 1024 + 4096);                   // N floats (400 KB)
    float2* node_pack = (float2*)(ws + 1024 + 4096 + (size_t)N_NODES * 4);  // N float2

    const int* srcp = edge_index;
    const int* dstp = edge_index + N_EDGES;

    // 391 blocks cover both the 100K nodes and the 256 tab1 blocks
    precompute_tab1<<<(N_NODES + 255) / 256, 256, 0, stream>>>(
        node_states, scalars,
        combine_W, keep_W, push_W, pushn_W, inc_W, training_step,
        node_pack, acc, out + N_EDGES, uv);

    tab_stage2<<<33, 256, 0, stream>>>(node_emb, edge_emb, combine_b,
                                       keep_W, keep_b, push_W, push_b,
                                       pushn_W, pushn_b, inc_W, inc_b,
                                       training_step, uv, tabs);

    const int ethreads = N_NONLOOP / 4;   // 225000
    edge_kernel<<<(ethreads + 255) / 256, 256, 0, stream>>>(
        scalars, srcp, dstp, brev, edge_states, node_pack, tabs, batch_scalars,
        acc, out, out + N_EDGES);

    finalize_nodes<<<(N_NODES + 255) / 256, 256, 0, stream>>>(
        brev, edge_states, node_pack, tabs, batch_scalars, acc, out, out + N_EDGES);
}